// Round 1
// baseline (2096.642 us; speedup 1.0000x reference)
//
#include <hip/hip_runtime.h>
#include <math.h>

#define S_ 2048
#define C_ 512
#define H_ 16
#define D_ 32
#define B_ 2
#define M_ (B_ * S_)             // 4096 tokens total
#define NSPLIT 4
#define SPLIT_LEN (S_ / NSPLIT)  // 512 keys per split
#define ROWS 64                  // query rows per block (= threads per block)
#define TN 32                    // key chunk staged in LDS
#define PSTRIDE 36               // floats per partial record: [0]=l, [4..36)=ctx
#define RSCALE 0.04419417382415922f  // 1/sqrt(512)

// ---------------- GEMM: O = X @ W^T (+ bias) ----------------
// X: [M_, 512] row-major, W: [512, 512] row-major (we dot rows of X with rows of W).
// transposed==1 stores O in [B, C, S] layout (for the pos projection).
__global__ __launch_bounds__(256) void gemm_xwT(const float* __restrict__ X,
                                                const float* __restrict__ W,
                                                const float* __restrict__ bias,
                                                float* __restrict__ O,
                                                int transposed) {
  __shared__ __align__(16) float As[16][64];  // As[k][m]
  __shared__ __align__(16) float Bs[16][64];  // Bs[k][n]
  const int tid = threadIdx.x;
  const int bm = blockIdx.y * 64;
  const int bn = blockIdx.x * 64;
  const int tm = (tid >> 4) * 4;   // 0..60
  const int tn = (tid & 15) * 4;   // 0..60
  const int lr = tid >> 2;         // 0..63
  const int lc = (tid & 3) * 4;    // 0,4,8,12
  float acc[4][4] = {};
  const float* Xp = X + (size_t)(bm + lr) * C_ + lc;
  const float* Wp = W + (size_t)(bn + lr) * C_ + lc;
  for (int k0 = 0; k0 < C_; k0 += 16) {
    float4 a = *(const float4*)(Xp + k0);
    float4 b = *(const float4*)(Wp + k0);
    __syncthreads();
    As[lc + 0][lr] = a.x; As[lc + 1][lr] = a.y; As[lc + 2][lr] = a.z; As[lc + 3][lr] = a.w;
    Bs[lc + 0][lr] = b.x; Bs[lc + 1][lr] = b.y; Bs[lc + 2][lr] = b.z; Bs[lc + 3][lr] = b.w;
    __syncthreads();
#pragma unroll
    for (int k = 0; k < 16; ++k) {
      float av[4], bv[4];
      *(float4*)av = *(const float4*)&As[k][tm];
      *(float4*)bv = *(const float4*)&Bs[k][tn];
#pragma unroll
      for (int i = 0; i < 4; ++i)
#pragma unroll
        for (int j = 0; j < 4; ++j) acc[i][j] += av[i] * bv[j];
    }
  }
#pragma unroll
  for (int i = 0; i < 4; ++i) {
    const int row = bm + tm + i;
#pragma unroll
    for (int j = 0; j < 4; ++j) {
      const int col = bn + tn + j;
      const float val = acc[i][j] + (bias ? bias[col] : 0.0f);
      if (!transposed) {
        O[(size_t)row * C_ + col] = val;
      } else {
        const int bb = row >> 11;        // row / S_
        const int t = row & (S_ - 1);    // row % S_
        O[((size_t)bb * C_ + col) * S_ + t] = val;
      }
    }
  }
}

// ---------------- Attention pass 1: split-K partials ----------------
// grid (NSPLIT, S_/ROWS, B_*H_), block = ROWS (1 wave). Thread owns one query row.
// PT layout: [B, C, S] so pos-row reads are stride-1 coalesced across lanes.
__global__ __launch_bounds__(64) void attn_partial(
    const float* __restrict__ Q, const float* __restrict__ K,
    const float* __restrict__ V, const float* __restrict__ PT,
    const float* __restrict__ u_bias, const float* __restrict__ v_bias,
    float* __restrict__ part) {
  __shared__ __align__(16) float Ks[TN][D_];
  __shared__ __align__(16) float Vs[TN][D_];
  const int tid = threadIdx.x;
  const int split = blockIdx.x;
  const int mblk = blockIdx.y;
  const int bh = blockIdx.z;
  const int b = bh >> 4, h = bh & 15;
  const int m = mblk * ROWS + tid;

  float qu[D_], qvc[D_], qvn[D_], ctx[D_];
  const float* Qrow = Q + ((size_t)(b * S_ + m)) * C_ + h * D_;
  const float* ub = u_bias + h * D_;
  const float* vb = v_bias + h * D_;
#pragma unroll
  for (int d = 0; d < D_; d += 4) {
    float q4[4], u4[4], v4[4];
    *(float4*)q4 = *(const float4*)(Qrow + d);
    *(float4*)u4 = *(const float4*)(ub + d);
    *(float4*)v4 = *(const float4*)(vb + d);
#pragma unroll
    for (int e = 0; e < 4; ++e) {
      qu[d + e] = q4[e] + u4[e];
      qvc[d + e] = q4[e] + v4[e];
    }
  }
  if (m + 1 < S_) {
    const float* Qn = Qrow + C_;
#pragma unroll
    for (int d = 0; d < D_; d += 4) {
      float q4[4], v4[4];
      *(float4*)q4 = *(const float4*)(Qn + d);
      *(float4*)v4 = *(const float4*)(vb + d);
#pragma unroll
      for (int e = 0; e < 4; ++e) qvn[d + e] = q4[e] + v4[e];
    }
  } else {
#pragma unroll
    for (int d = 0; d < D_; ++d) qvn[d] = 0.0f;  // never used (u>=2 impossible at m=S-1)
  }
#pragma unroll
  for (int d = 0; d < D_; ++d) ctx[d] = 0.0f;
  float l = 0.0f;

  const float* PTbh = PT + ((size_t)(b * C_ + h * D_)) * S_;
  const size_t kvbase = ((size_t)(b * S_)) * C_ + h * D_;
  const int n0 = split * SPLIT_LEN;

#pragma unroll 1
  for (int c = 0; c < SPLIT_LEN / TN; ++c) {
    const int nc = n0 + c * TN;
    __syncthreads();
#pragma unroll
    for (int i = 0; i < (TN * D_) / (4 * ROWS); ++i) {  // 4 float4 per thread per array
      const int f = i * ROWS + tid;
      const int row = f >> 3;
      const int col = (f & 7) << 2;
      *(float4*)&Ks[row][col] = *(const float4*)&K[kvbase + (size_t)(nc + row) * C_ + col];
      *(float4*)&Vs[row][col] = *(const float4*)&V[kvbase + (size_t)(nc + row) * C_ + col];
    }
    __syncthreads();
#pragma unroll 1
    for (int nn = 0; nn < TN; ++nn) {
      const int n = nc + nn;
      // content score: qu . K[n]  (LDS broadcast reads)
      float sc = 0.0f;
#pragma unroll
      for (int d = 0; d < D_; d += 4) {
        float k4[4];
        *(float4*)k4 = *(const float4*)&Ks[nn][d];
        sc += qu[d] * k4[0] + qu[d + 1] * k4[1] + qu[d + 2] * k4[2] + qu[d + 3] * k4[3];
      }
      // skewed positional score
      float sp = 0.0f;
      const int u = n - m;
      if (u <= 0) {
        const float* pr = PTbh + (S_ - 1 + u);   // PS[m][S-1+u]
#pragma unroll
        for (int d = 0; d < D_; ++d) sp += qvc[d] * pr[(size_t)d * S_];
      } else if (u >= 2) {
        const float* pr = PTbh + (u - 2);        // PS[m+1][u-2]
#pragma unroll
        for (int d = 0; d < D_; ++d) sp += qvn[d] * pr[(size_t)d * S_];
      }
      // |score| <= ~3.2 << 88, so plain exp is safe in fp32 (no online max)
      const float p = __expf((sc + sp) * RSCALE);
      l += p;
#pragma unroll
      for (int d = 0; d < D_; d += 4) {
        float v4[4];
        *(float4*)v4 = *(const float4*)&Vs[nn][d];
        ctx[d] += p * v4[0]; ctx[d + 1] += p * v4[1];
        ctx[d + 2] += p * v4[2]; ctx[d + 3] += p * v4[3];
      }
    }
  }
  float* pp = part + ((size_t)((bh * NSPLIT + split) * S_ + m)) * PSTRIDE;
  pp[0] = l;
#pragma unroll
  for (int d = 0; d < D_; d += 4) {
    *(float4*)&pp[4 + d] = make_float4(ctx[d], ctx[d + 1], ctx[d + 2], ctx[d + 3]);
  }
}

// ---------------- Attention pass 2: merge splits ----------------
__global__ __launch_bounds__(256) void attn_merge(const float* __restrict__ part,
                                                  float* __restrict__ ctxo) {
  const int g = blockIdx.x * 256 + threadIdx.x;  // [0, B_*H_*S_)
  const int bh = g >> 11;                        // g / S_
  const int s = g & (S_ - 1);
  const int b = bh >> 4, h = bh & 15;
  float L = 0.0f;
  float acc[D_];
#pragma unroll
  for (int d = 0; d < D_; ++d) acc[d] = 0.0f;
#pragma unroll
  for (int j = 0; j < NSPLIT; ++j) {
    const float* pp = part + ((size_t)((bh * NSPLIT + j) * S_ + s)) * PSTRIDE;
    L += pp[0];
#pragma unroll
    for (int d = 0; d < D_; d += 4) {
      float c4[4];
      *(float4*)c4 = *(const float4*)&pp[4 + d];
      acc[d] += c4[0]; acc[d + 1] += c4[1]; acc[d + 2] += c4[2]; acc[d + 3] += c4[3];
    }
  }
  const float inv = 1.0f / L;
  float* o = ctxo + ((size_t)(b * S_ + s)) * C_ + h * D_;
#pragma unroll
  for (int d = 0; d < D_; d += 4) {
    *(float4*)&o[d] = make_float4(acc[d] * inv, acc[d + 1] * inv,
                                  acc[d + 2] * inv, acc[d + 3] * inv);
  }
}

extern "C" void kernel_launch(void* const* d_in, const int* in_sizes, int n_in,
                              void* d_out, int out_size, void* d_ws, size_t ws_size,
                              hipStream_t stream) {
  (void)in_sizes; (void)n_in; (void)out_size; (void)ws_size;
  const float* q  = (const float*)d_in[0];
  const float* k  = (const float*)d_in[1];
  const float* v  = (const float*)d_in[2];
  const float* pe = (const float*)d_in[3];
  const float* Wq = (const float*)d_in[4];
  const float* bq = (const float*)d_in[5];
  const float* Wk = (const float*)d_in[6];
  const float* bk = (const float*)d_in[7];
  const float* Wv = (const float*)d_in[8];
  const float* bv = (const float*)d_in[9];
  const float* Wp = (const float*)d_in[10];
  const float* ub = (const float*)d_in[11];
  const float* vb = (const float*)d_in[12];
  const float* Wo = (const float*)d_in[13];
  const float* bo = (const float*)d_in[14];
  float* out = (float*)d_out;

  float* ws = (float*)d_ws;
  const size_t MC = (size_t)M_ * C_;  // 2M floats
  float* Qb  = ws;
  float* Kb  = Qb + MC;
  float* Vb  = Kb + MC;
  float* PTb = Vb + MC;     // [B, C, S]
  float* CTX = PTb + MC;
  float* PART = CTX + MC;   // 32*4*2048*36 floats = ~37.7 MB

  dim3 ggrid(C_ / 64, M_ / 64);
  gemm_xwT<<<ggrid, 256, 0, stream>>>(q, Wq, bq, Qb, 0);
  gemm_xwT<<<ggrid, 256, 0, stream>>>(k, Wk, bk, Kb, 0);
  gemm_xwT<<<ggrid, 256, 0, stream>>>(v, Wv, bv, Vb, 0);
  gemm_xwT<<<ggrid, 256, 0, stream>>>(pe, Wp, nullptr, PTb, 1);
  attn_partial<<<dim3(NSPLIT, S_ / ROWS, B_ * H_), ROWS, 0, stream>>>(
      Qb, Kb, Vb, PTb, ub, vb, PART);
  attn_merge<<<dim3((B_ * H_ * S_) / 256), 256, 0, stream>>>(PART, CTX);
  gemm_xwT<<<ggrid, 256, 0, stream>>>(CTX, Wo, bo, out, 0);
}

// Round 4
// 476.275 us; speedup vs baseline: 4.4022x; 4.4022x over previous
//
#include <hip/hip_runtime.h>
#include <math.h>

#define S_ 2048
#define C_ 512
#define H_ 16
#define D_ 32
#define B_ 2
#define M_ (B_ * S_)
#define RSCALE 0.04419417382415922f  // 1/sqrt(512)

typedef __attribute__((ext_vector_type(8))) short bf16x8;
typedef __attribute__((ext_vector_type(4))) float f32x4;

__device__ inline unsigned short f2bf(float f) {
  unsigned u = __builtin_bit_cast(unsigned, f);
  u += 0x7FFFu + ((u >> 16) & 1u);
  return (unsigned short)(u >> 16);
}

// ---------------- GEMM: O = X @ W^T (+bias), epilogue per mode ----------------
// mode 0: fp32 [M][C] (+bias)           -> Of
// mode 1: bf16 QU/QV [B][H][S][D], +bias+bias2 / +bias+bias3 -> Ob, Ob2
// mode 2: bf16 [B][H][S][D] (+bias if non-null)              -> Ob   (K, POS)
// mode 3: bf16 [B][H][D][S] transposed (+bias)               -> Ob   (V)
__global__ __launch_bounds__(256) void gemm_xwT(
    const float* __restrict__ X, const float* __restrict__ W,
    const float* __restrict__ bias, const float* __restrict__ bias2,
    const float* __restrict__ bias3, float* __restrict__ Of,
    short* __restrict__ Ob, short* __restrict__ Ob2, int mode) {
  __shared__ __align__(16) float As[16][64];
  __shared__ __align__(16) float Bs[16][64];
  const int tid = threadIdx.x;
  const int bm = blockIdx.y * 64;
  const int bn = blockIdx.x * 64;
  const int tm = (tid >> 4) * 4;
  const int tn = (tid & 15) * 4;
  const int lr = tid >> 2;
  const int lc = (tid & 3) * 4;
  float acc[4][4] = {};
  const float* Xp = X + (size_t)(bm + lr) * C_ + lc;
  const float* Wp = W + (size_t)(bn + lr) * C_ + lc;
  for (int k0 = 0; k0 < C_; k0 += 16) {
    float4 a = *(const float4*)(Xp + k0);
    float4 b = *(const float4*)(Wp + k0);
    __syncthreads();
    As[lc + 0][lr] = a.x; As[lc + 1][lr] = a.y; As[lc + 2][lr] = a.z; As[lc + 3][lr] = a.w;
    Bs[lc + 0][lr] = b.x; Bs[lc + 1][lr] = b.y; Bs[lc + 2][lr] = b.z; Bs[lc + 3][lr] = b.w;
    __syncthreads();
#pragma unroll
    for (int k = 0; k < 16; ++k) {
      float av[4], bv[4];
      *(float4*)av = *(const float4*)&As[k][tm];
      *(float4*)bv = *(const float4*)&Bs[k][tn];
#pragma unroll
      for (int i = 0; i < 4; ++i)
#pragma unroll
        for (int j = 0; j < 4; ++j) acc[i][j] += av[i] * bv[j];
    }
  }
  const int col0 = bn + tn;
  const int row0 = bm + tm;
  if (mode == 0) {
#pragma unroll
    for (int i = 0; i < 4; ++i) {
#pragma unroll
      for (int j = 0; j < 4; ++j)
        Of[(size_t)(row0 + i) * C_ + col0 + j] = acc[i][j] + (bias ? bias[col0 + j] : 0.0f);
    }
  } else if (mode == 1) {
    const int h = col0 >> 5, d0 = col0 & 31;
#pragma unroll
    for (int i = 0; i < 4; ++i) {
      const int row = row0 + i;
      const int bb = row >> 11, s = row & (S_ - 1);
      const size_t base = ((size_t)(bb * H_ + h) * S_ + s) * D_ + d0;
      ushort4 qu, qv;
      unsigned short* pu = (unsigned short*)&qu;
      unsigned short* pv = (unsigned short*)&qv;
#pragma unroll
      for (int j = 0; j < 4; ++j) {
        const float val = acc[i][j] + bias[col0 + j];
        pu[j] = f2bf(val + bias2[col0 + j]);
        pv[j] = f2bf(val + bias3[col0 + j]);
      }
      *(ushort4*)(Ob + base) = qu;
      *(ushort4*)(Ob2 + base) = qv;
    }
  } else if (mode == 2) {
    const int h = col0 >> 5, d0 = col0 & 31;
#pragma unroll
    for (int i = 0; i < 4; ++i) {
      const int row = row0 + i;
      const int bb = row >> 11, s = row & (S_ - 1);
      const size_t base = ((size_t)(bb * H_ + h) * S_ + s) * D_ + d0;
      ushort4 kv;
      unsigned short* pk = (unsigned short*)&kv;
#pragma unroll
      for (int j = 0; j < 4; ++j)
        pk[j] = f2bf(acc[i][j] + (bias ? bias[col0 + j] : 0.0f));
      *(ushort4*)(Ob + base) = kv;
    }
  } else {  // mode 3: transposed [B][H][D][S]
    const int bb = row0 >> 11, s0 = row0 & (S_ - 1);
#pragma unroll
    for (int j = 0; j < 4; ++j) {
      const int colj = col0 + j;
      const int h = colj >> 5, d = colj & 31;
      const float bb_ = bias ? bias[colj] : 0.0f;
      ushort4 vv;
      unsigned short* pvv = (unsigned short*)&vv;
#pragma unroll
      for (int i = 0; i < 4; ++i) pvv[i] = f2bf(acc[i][j] + bb_);
      *(ushort4*)(Ob + ((size_t)(bb * H_ + h) * D_ + d) * S_ + s0) = vv;
    }
  }
}

// ---------------- Fused relative attention, MFMA flash ----------------
// grid (S/64, B*H), block 256 (4 waves). Wave w owns output rows [16w,16w+16).
// Score(m,n) = QU[m].K[n] + posband;  posband via QV.POS^T band MFMA + diagonal gather.
__global__ __launch_bounds__(256, 4) void attn_mfma(
    const short* __restrict__ QU, const short* __restrict__ QV,
    const short* __restrict__ Kb, const short* __restrict__ Vt,
    const short* __restrict__ POSb, float* __restrict__ CTX) {
  __shared__ float PB[64 * 128];   // 32 KB band buffer (swizzled cols)
  __shared__ short Pl[64 * 64];    // 8 KB P tile bf16 (swizzled cols)
  const int tid = threadIdx.x;
  const int w = tid >> 6;
  const int lane = tid & 63;
  const int col = lane & 15;
  const int quad = lane >> 4;
  const int m0 = blockIdx.x * 64;
  const int bh = blockIdx.y;
  const int b = bh >> 4, h = bh & 15;

  const short* QUh = QU + (size_t)bh * S_ * D_;
  const short* QVh = QV + (size_t)bh * S_ * D_;
  const short* Kh = Kb + (size_t)bh * S_ * D_;
  const short* Vh = Vt + (size_t)bh * D_ * S_;
  const short* Ph = POSb + (size_t)bh * S_ * D_;

  // Persistent A-fragments (A[m=lane&15][k=quad*8+j])
  const int arow = m0 + 16 * w + col;
  const bf16x8 aQU = *(const bf16x8*)(QUh + (size_t)arow * D_ + quad * 8);
  const bf16x8 aQVA = *(const bf16x8*)(QVh + (size_t)arow * D_ + quad * 8);
  // band B uses QV rows +1; row==S_ only at last tile where result is never gathered
  const bf16x8 aQVB = *(const bf16x8*)(QVh + (size_t)(arow + 1) * D_ + quad * 8);

  const f32x4 zc = {0.f, 0.f, 0.f, 0.f};
  const bf16x8 zb = {0, 0, 0, 0, 0, 0, 0, 0};
  f32x4 ctxa0 = zc, ctxa1 = zc;
  float lpart[4] = {0.f, 0.f, 0.f, 0.f};
  const int mi0 = 16 * w + 4 * quad;

  for (int ch = 0; ch < 32; ++ch) {
    const int n0 = ch * 64;
    const int dnm = n0 - m0;
    // content scores: 4 col-tiles of 16
    f32x4 sc[4];
#pragma unroll
    for (int j = 0; j < 4; ++j) {
      bf16x8 bk = *(const bf16x8*)(Kh + (size_t)(n0 + 16 * j + col) * D_ + quad * 8);
      sc[j] = __builtin_amdgcn_mfma_f32_16x16x32_bf16(aQU, bk, zc, 0, 0, 0);
    }
    // ---- band A: PS[m][S-1+u] for u<=0 ----
    if (dnm <= 63) {
      const int tA0 = S_ - 64 + dnm;  // >= 0 always
#pragma unroll
      for (int j = 0; j < 8; ++j) {
        const int t = tA0 + 16 * j + col;
        bf16x8 bp = *(const bf16x8*)(Ph + (long)t * D_ + quad * 8);
        if (t >= S_) bp = zb;
        f32x4 c = __builtin_amdgcn_mfma_f32_16x16x32_bf16(aQVA, bp, zc, 0, 0, 0);
#pragma unroll
        for (int r = 0; r < 4; ++r) {
          const int mi = mi0 + r;
          const int cc = (16 * j + col) ^ (((mi & 4) << 2) ^ ((mi & 3) << 3));
          PB[mi * 128 + cc] = c[r];
        }
      }
      __syncthreads();
#pragma unroll
      for (int j = 0; j < 4; ++j)
#pragma unroll
        for (int r = 0; r < 4; ++r) {
          const int mi = mi0 + r;
          const int nj = 16 * j + col;
          if (dnm + nj - mi <= 0) {  // n <= m
            const int idx = (nj - mi + 63) ^ (((mi & 4) << 2) ^ ((mi & 3) << 3));
            sc[j][r] += PB[mi * 128 + idx];
          }
        }
    }
    // ---- band B: PS[m+1][u-2] for u>=2 ----
    if (dnm >= -61) {
      __syncthreads();  // gather-A reads done before overwrite
      const int tB0 = dnm - 65;
#pragma unroll
      for (int j = 0; j < 8; ++j) {
        const int t = tB0 + 16 * j + col;
        bf16x8 bp = *(const bf16x8*)(Ph + (long)t * D_ + quad * 8);
        if (t < 0) bp = zb;
        f32x4 c = __builtin_amdgcn_mfma_f32_16x16x32_bf16(aQVB, bp, zc, 0, 0, 0);
#pragma unroll
        for (int r = 0; r < 4; ++r) {
          const int mi = mi0 + r;
          const int cc = (16 * j + col) ^ (((mi & 4) << 2) ^ ((mi & 3) << 3));
          PB[mi * 128 + cc] = c[r];
        }
      }
      __syncthreads();
#pragma unroll
      for (int j = 0; j < 4; ++j)
#pragma unroll
        for (int r = 0; r < 4; ++r) {
          const int mi = mi0 + r;
          const int nj = 16 * j + col;
          if (dnm + nj - mi >= 2) {  // n >= m+2
            const int idx = (nj - mi + 63) ^ (((mi & 4) << 2) ^ ((mi & 3) << 3));
            sc[j][r] += PB[mi * 128 + idx];
          }
        }
    }
    // ---- exp, row-sum accumulate, P -> LDS (bf16) ----
    __syncthreads();  // prev chunk's PV reads of Pl complete
#pragma unroll
    for (int j = 0; j < 4; ++j)
#pragma unroll
      for (int r = 0; r < 4; ++r) {
        const float p = __expf(sc[j][r] * RSCALE);
        lpart[r] += p;
        const int mi = mi0 + r;
        const int cc = (16 * j + col) ^ ((mi & 7) << 3);
        Pl[mi * 64 + cc] = (short)f2bf(p);
      }
    __syncthreads();
    // ---- PV: ctx += P @ V ----
    const int prow = 16 * w + col;
    const int psw = (prow & 7) << 3;
#pragma unroll
    for (int k0 = 0; k0 < 2; ++k0) {
      const bf16x8 ap = *(const bf16x8*)(&Pl[prow * 64 + ((k0 * 32 + quad * 8) ^ psw)]);
      bf16x8 bv0 = *(const bf16x8*)(Vh + (size_t)col * S_ + n0 + k0 * 32 + quad * 8);
      ctxa0 = __builtin_amdgcn_mfma_f32_16x16x32_bf16(ap, bv0, ctxa0, 0, 0, 0);
      bf16x8 bv1 = *(const bf16x8*)(Vh + (size_t)(16 + col) * S_ + n0 + k0 * 32 + quad * 8);
      ctxa1 = __builtin_amdgcn_mfma_f32_16x16x32_bf16(ap, bv1, ctxa1, 0, 0, 0);
    }
  }
  // ---- epilogue: reduce row sums across 16-lane groups, normalize, store ----
#pragma unroll
  for (int r = 0; r < 4; ++r) {
    float s = lpart[r];
    s += __shfl_xor(s, 1);
    s += __shfl_xor(s, 2);
    s += __shfl_xor(s, 4);
    s += __shfl_xor(s, 8);
    lpart[r] = 1.0f / s;
  }
  const int mrow = m0 + mi0;
#pragma unroll
  for (int r = 0; r < 4; ++r) {
    const size_t obase = ((size_t)(b * S_ + mrow + r)) * C_ + h * D_;
    CTX[obase + col] = ctxa0[r] * lpart[r];
    CTX[obase + 16 + col] = ctxa1[r] * lpart[r];
  }
}

extern "C" void kernel_launch(void* const* d_in, const int* in_sizes, int n_in,
                              void* d_out, int out_size, void* d_ws, size_t ws_size,
                              hipStream_t stream) {
  (void)in_sizes; (void)n_in; (void)out_size; (void)ws_size;
  const float* q = (const float*)d_in[0];
  const float* k = (const float*)d_in[1];
  const float* v = (const float*)d_in[2];
  const float* pe = (const float*)d_in[3];
  const float* Wq = (const float*)d_in[4];
  const float* bq = (const float*)d_in[5];
  const float* Wk = (const float*)d_in[6];
  const float* bk = (const float*)d_in[7];
  const float* Wv = (const float*)d_in[8];
  const float* bv = (const float*)d_in[9];
  const float* Wp = (const float*)d_in[10];
  const float* ub = (const float*)d_in[11];
  const float* vb = (const float*)d_in[12];
  const float* Wo = (const float*)d_in[13];
  const float* bo = (const float*)d_in[14];
  float* out = (float*)d_out;

  const size_t MC = (size_t)M_ * C_;
  short* QUb = (short*)d_ws;
  short* QVb = QUb + MC;
  short* Kbb = QVb + MC;
  short* Vtb = Kbb + MC;
  short* POSB = Vtb + MC;
  float* CTX = (float*)(POSB + MC);

  dim3 ggrid(C_ / 64, M_ / 64);
  gemm_xwT<<<ggrid, 256, 0, stream>>>(q, Wq, bq, ub, vb, nullptr, QUb, QVb, 1);
  gemm_xwT<<<ggrid, 256, 0, stream>>>(k, Wk, bk, nullptr, nullptr, nullptr, Kbb, nullptr, 2);
  gemm_xwT<<<ggrid, 256, 0, stream>>>(v, Wv, bv, nullptr, nullptr, nullptr, Vtb, nullptr, 3);
  gemm_xwT<<<ggrid, 256, 0, stream>>>(pe, Wp, nullptr, nullptr, nullptr, nullptr, POSB, nullptr, 2);
  attn_mfma<<<dim3(S_ / 64, B_ * H_), 256, 0, stream>>>(QUb, QVb, Kbb, Vtb, POSB, CTX);
  gemm_xwT<<<ggrid, 256, 0, stream>>>(CTX, Wo, bo, nullptr, nullptr, out, nullptr, nullptr, 0);
}